// Round 3
// baseline (494.895 us; speedup 1.0000x reference)
//
#include <hip/hip_runtime.h>
#include <hip/hip_bf16.h>

// LQLinear: out = x @ quantize(weight, basis)^T + bias
// M=8192 tokens, N=4096 out_features, K=4096 in_features.
// Q_T=1 and new_basis is discarded => the LSQ refit does NOT affect output.

#define M_TOK 8192
#define N_OUT 4096
#define K_IN  4096

typedef __attribute__((ext_vector_type(8))) short short8;     // 8 bf16 (4 VGPRs)
typedef __attribute__((ext_vector_type(16))) float floatx16;  // 32x32 MFMA C/D

typedef __attribute__((address_space(1))) const void gvoid_t;
typedef __attribute__((address_space(3))) void lvoid_t;

// round-to-nearest-even fp32 -> bf16 (bit trick; no NaN in this data)
__device__ __forceinline__ ushort f2bf(float f) {
    unsigned u = __float_as_uint(f);
    u += 0x7fffu + ((u >> 16) & 1u);
    return (ushort)(u >> 16);
}

// ---------------- fused prep: x fp32->bf16  +  weight quantize ----------------
#define PREP_XBLK 2048
#define PREP_WBLK 1024

__global__ __launch_bounds__(256) void prep(
        const float4* __restrict__ x,  short8* __restrict__ xb,
        const float4* __restrict__ w,  const float* __restrict__ basis,
        short8* __restrict__ wqo) {
    if (blockIdx.x < PREP_XBLK) {
        const int tid    = blockIdx.x * 256 + threadIdx.x;
        const int stride = PREP_XBLK * 256;
        const int n8     = (M_TOK * K_IN) / 8;
        for (int i = tid; i < n8; i += stride) {
            float4 a = x[2 * i], b = x[2 * i + 1];
            short8 o;
            o[0] = (short)f2bf(a.x); o[1] = (short)f2bf(a.y);
            o[2] = (short)f2bf(a.z); o[3] = (short)f2bf(a.w);
            o[4] = (short)f2bf(b.x); o[5] = (short)f2bf(b.y);
            o[6] = (short)f2bf(b.z); o[7] = (short)f2bf(b.w);
            xb[i] = o;
        }
    } else {
        float b0 = basis[0], b1 = basis[1];
        float l0 = -b0 - b1, l1 = -b0 + b1, l2 = b0 - b1, l3 = b0 + b1;
        float t;
        if (l0 > l1) { t = l0; l0 = l1; l1 = t; }
        if (l2 > l3) { t = l2; l2 = l3; l3 = t; }
        if (l0 > l2) { t = l0; l0 = l2; l2 = t; }
        if (l1 > l3) { t = l1; l1 = l3; l3 = t; }
        if (l1 > l2) { t = l1; l1 = l2; l2 = t; }
        const float t0 = 0.5f * (l0 + l1), t1 = 0.5f * (l1 + l2), t2 = 0.5f * (l2 + l3);
        const int tid    = (blockIdx.x - PREP_XBLK) * 256 + threadIdx.x;
        const int stride = PREP_WBLK * 256;
        const int n8     = (N_OUT * K_IN) / 8;
#define QF(vv) ((vv > t1) ? ((vv > t2) ? l3 : l2) : ((vv > t0) ? l1 : l0))
        for (int i = tid; i < n8; i += stride) {
            float4 a = w[2 * i], b = w[2 * i + 1];
            short8 o;
            o[0] = (short)f2bf(QF(a.x)); o[1] = (short)f2bf(QF(a.y));
            o[2] = (short)f2bf(QF(a.z)); o[3] = (short)f2bf(QF(a.w));
            o[4] = (short)f2bf(QF(b.x)); o[5] = (short)f2bf(QF(b.y));
            o[6] = (short)f2bf(QF(b.z)); o[7] = (short)f2bf(QF(b.w));
            wqo[i] = o;
        }
#undef QF
    }
}

// ---------------- GEMM 256x256, BK=64, 8-phase, 32x32x16 MFMA ---------------
// C[M][N] = A[M][K] * B[N][K]^T + bias.
// 512 threads = 8 waves (2 M x 4 N), per-wave output 128x64:
//   4 A-frags (32 rows) x 2 B-frags (32 cols) x 4 ksteps of K=16
//   => 32 x v_mfma_f32_32x32x16_bf16 per K-tile (2382-2495 TF ubench ceiling,
//      +15% over 16x16x32's 2075).
// LDS 128KiB: As[2][256*64] + Bs[2][256*64] bf16, buffer parity = K-tile parity.
// 8 phases / 2 K-tiles; phase = {ds_reads, stage 1 half-tile, bar, 8 MFMA
// (setprio), bar}. Read plan [12,4,4,4]: ph_i computes A-frag i; B fully
// consumed after ph1, A rows 0-63 after ph2 => per-phase stages into the
// CURRENTLY-READ buffer are read-safe:
//   ph1: (t+1).A1 | ph2: (t+2).B0 | ph3: (t+2).B1 | ph4: (t+2).A0 + vmcnt(6)
// vmcnt(6) = 3 half-tiles (2 loads each) in flight; at ph4 it proves all of
// (t+1) landed before the next group reads buffer (t+1)&1.
// LDS XOR swizzle (verified 0 conflicts): physical 16B chunk c of row r holds
// global chunk c^(r&7); staging pre-swizzles the GLOBAL source address so the
// linear global_load_lds destination stays contiguous.

#define NIT 32   // iterations; 2 K-tiles each; K = 64 tiles of BK=64

// plain barrier + compiler memory fence (no sched_barrier: ds_reads are C++
// derefs so the compiler tracks lgkm deps; leaving the scheduler free lets it
// pre-compute next-phase addresses inside MFMA regions)
#define BARm() do { asm volatile("" ::: "memory"); \
                    __builtin_amdgcn_s_barrier(); \
                    asm volatile("" ::: "memory"); } while (0)
#define VMC6() asm volatile("s_waitcnt vmcnt(6)" ::: "memory")
#define VMC0() asm volatile("s_waitcnt vmcnt(0)" ::: "memory")

// stage half h (128 rows) of K-tile tt of A/B into its parity buffer.
// per wave: 2 instrs, each 8 rows x 64 cols (64 lanes x 16B).
#define STAGE_A(tt, h) do { const int _p = (tt) & 1;                          \
    __builtin_amdgcn_global_load_lds(                                         \
        (gvoid_t*)(ag + (size_t)((h) * 128) * K_IN + (tt) * 64),              \
        (lvoid_t*)(As + _p * 16384 + ((h) * 128 + wid * 16) * 64), 16, 0, 0); \
    __builtin_amdgcn_global_load_lds(                                         \
        (gvoid_t*)(ag + (size_t)((h) * 128 + 8) * K_IN + (tt) * 64),          \
        (lvoid_t*)(As + _p * 16384 + ((h) * 128 + wid * 16 + 8) * 64), 16, 0, 0); \
} while (0)
#define STAGE_B(tt, h) do { const int _p = (tt) & 1;                          \
    __builtin_amdgcn_global_load_lds(                                         \
        (gvoid_t*)(bg + (size_t)((h) * 128) * K_IN + (tt) * 64),              \
        (lvoid_t*)(Bs + _p * 16384 + ((h) * 128 + wid * 16) * 64), 16, 0, 0); \
    __builtin_amdgcn_global_load_lds(                                         \
        (gvoid_t*)(bg + (size_t)((h) * 128 + 8) * K_IN + (tt) * 64),          \
        (lvoid_t*)(Bs + _p * 16384 + ((h) * 128 + wid * 16 + 8) * 64), 16, 0, 0); \
} while (0)

// read A-frag FI (4 ksteps) from the current buffer
#define READ_A(FI) do {                                                       \
    _Pragma("unroll") for (int s = 0; s < 4; ++s)                             \
        av[s] = *(const short8*)(Ab + (FI) * 2048 + csz[s]);                  \
} while (0)

// 8 MFMAs: A-frag FI x {B-frag 0,1} x 4 ksteps; 2 independent acc chains
#define MFMA_PH(FI) do {                                                      \
    __builtin_amdgcn_s_setprio(1);                                            \
    _Pragma("unroll") for (int s = 0; s < 4; ++s) {                           \
        acc[FI][0] = __builtin_amdgcn_mfma_f32_32x32x16_bf16(                 \
            av[s], bf[0][s], acc[FI][0], 0, 0, 0);                            \
        acc[FI][1] = __builtin_amdgcn_mfma_f32_32x32x16_bf16(                 \
            av[s], bf[1][s], acc[FI][1], 0, 0, 0);                            \
    }                                                                         \
    __builtin_amdgcn_s_setprio(0);                                            \
} while (0)

// one 4-phase group = one K-tile from buffer parity PB.
#define GROUP4(PB, TS1, C1, TS2, CM) do {                                     \
    const ushort* Ab = As + (PB) * 16384 + (wm + mrow32) * 64;                \
    const ushort* Bb = Bs + (PB) * 16384 + (wn + mrow32) * 64;                \
    short8 av[4], bf[2][4];                                                   \
    /* phase 1: all B (8 reads) + A-frag0 (4 reads) */                        \
    _Pragma("unroll") for (int s = 0; s < 4; ++s) {                           \
        bf[0][s] = *(const short8*)(Bb + csz[s]);                             \
        bf[1][s] = *(const short8*)(Bb + 2048 + csz[s]);                      \
    }                                                                         \
    READ_A(0);                                                                \
    if (C1) { STAGE_A(TS1, 1); }                                              \
    BARm();                                                                   \
    MFMA_PH(0);                                                               \
    BARm();                                                                   \
    /* phase 2: A-frag1 */                                                    \
    READ_A(1);                                                                \
    if (CM) { STAGE_B(TS2, 0); }                                              \
    BARm();                                                                   \
    MFMA_PH(1);                                                               \
    BARm();                                                                   \
    /* phase 3: A-frag2 */                                                    \
    READ_A(2);                                                                \
    if (CM) { STAGE_B(TS2, 1); }                                              \
    BARm();                                                                   \
    MFMA_PH(2);                                                               \
    BARm();                                                                   \
    /* phase 4: A-frag3 */                                                    \
    READ_A(3);                                                                \
    if (CM) { STAGE_A(TS2, 0); VMC6(); } else { VMC0(); }                     \
    BARm();                                                                   \
    MFMA_PH(3);                                                               \
    BARm();                                                                   \
} while (0)

extern "C" __global__ __launch_bounds__(512, 2) void gemm256(
        const ushort* __restrict__ A,   // bf16 [M][K]
        const ushort* __restrict__ B,   // bf16 [N][K]
        const float* __restrict__ bias, // [N]
        float* __restrict__ C) {        // fp32 [M][N]
    extern __shared__ ushort smem[];    // 128 KiB
    ushort* As = smem;                  // [2][256*64]
    ushort* Bs = smem + 32768;          // [2][256*64]

    const int tid  = threadIdx.x;
    const int lane = tid & 63;
    const int wid  = tid >> 6;          // 0..7
    const int wr   = wid >> 2;          // 0..1
    const int wc   = wid & 3;           // 0..3
    const int wm   = wr * 128;          // wave row offset in 256 tile
    const int wn   = wc * 64;           // wave col offset

    // bijective XCD swizzle: 512 blocks, 512 % 8 == 0
    const int bid = blockIdx.x;
    const int swz = (bid & 7) * 64 + (bid >> 3);
    const int bn0 = (swz & 15) * 256;   // N/256 = 16
    const int bm0 = (swz >> 4) * 256;   // M/256 = 32

    // staging source (pre-swizzled global chunk = lc ^ lr)
    const int lr = lane >> 3, lc = lane & 7;
    const ushort* ag = A + (size_t)(bm0 + wid * 16 + lr) * K_IN + (lc ^ lr) * 8;
    const ushort* bg = B + (size_t)(bn0 + wid * 16 + lr) * K_IN + (lc ^ lr) * 8;

    // 32x32x16 fragment addressing: lane = (half, mrow32);
    // A/B elem j of reg-block s sits at k = s*16 + half*8 + j.
    // Logical 16B chunk = s*2 + half; physical = chunk ^ (row&7); since all
    // frag row bases are multiples of 32, row&7 == mrow32&7.
    const int mrow32 = lane & 31;
    const int half   = lane >> 5;
    int csz[4];
#pragma unroll
    for (int s = 0; s < 4; ++s)
        csz[s] = (((2 * s) | half) ^ (mrow32 & 7)) * 8;   // ushort offset

    floatx16 acc[4][2] = {};

    // prologue: tile0 fully + tile1 {B0,B1,A0}; vmcnt(6) proves tile0 landed
    STAGE_B(0, 0); STAGE_B(0, 1); STAGE_A(0, 0); STAGE_A(0, 1);
    STAGE_B(1, 0); STAGE_B(1, 1); STAGE_A(1, 0);
    VMC6();
    BARm();

#pragma unroll 1
    for (int it = 0; it < NIT; ++it) {
        const bool more = (it + 1 < NIT);
        GROUP4(0, 2 * it + 1, true, 2 * it + 2, more);
        GROUP4(1, 2 * it + 2, more, 2 * it + 3, more);
    }

    // epilogue: 32x32 C/D layout col=lane&31, row=(reg&3)+8*(reg>>2)+4*half
    const int cc = lane & 31;
#pragma unroll
    for (int nj = 0; nj < 2; ++nj) {
        const int col = bn0 + wn + nj * 32 + cc;
        const float bj = bias[col];
#pragma unroll
        for (int mi = 0; mi < 4; ++mi) {
#pragma unroll
            for (int r = 0; r < 16; ++r) {
                const int row = bm0 + wm + mi * 32 + (r & 3) + 8 * (r >> 2) + 4 * half;
                C[(size_t)row * N_OUT + col] = acc[mi][nj][r] + bj;
            }
        }
    }
}

extern "C" void kernel_launch(void* const* d_in, const int* in_sizes, int n_in,
                              void* d_out, int out_size, void* d_ws, size_t ws_size,
                              hipStream_t stream) {
    const float* x     = (const float*)d_in[0];  // [8192,4096]
    const float* w     = (const float*)d_in[1];  // [4096,4096]
    const float* bias  = (const float*)d_in[2];  // [4096]
    const float* basis = (const float*)d_in[3];  // [2]
    float* out = (float*)d_out;                  // [8192,4096] fp32

    ushort* Xb = (ushort*)d_ws;                      // 8192*4096 bf16 = 67.1 MB
    ushort* Wq = Xb + (size_t)M_TOK * K_IN;          // 4096*4096 bf16 = 33.5 MB

    prep<<<PREP_XBLK + PREP_WBLK, 256, 0, stream>>>(
        (const float4*)x, (short8*)Xb, (const float4*)w, basis, (short8*)Wq);

    // 128 KiB dynamic LDS needs the attribute raised past the 64 KiB default
    (void)hipFuncSetAttribute((const void*)gemm256,
                              hipFuncAttributeMaxDynamicSharedMemorySize, 131072);
    gemm256<<<dim3(512), 512, 131072, stream>>>(Xb, Wq, bias, out);
}